// Round 6
// baseline (224.620 us; speedup 1.0000x reference)
//
#include <hip/hip_runtime.h>

#define B_ 2
#define S_ 2048
#define DM_ 1024
#define H_ 16
#define HD_ 64
// Q pre-scale = HD^-0.5 * log2(e) so attention uses exp2 (bare v_exp_f32).
#define QSCALE_ 0.18033688011112042f

// Settled R0-R4: inputs fp32 (bf16-rounded values), output fp32.
typedef __bf16 bf16;
typedef __attribute__((ext_vector_type(4))) __bf16 bf16x4;
typedef __attribute__((ext_vector_type(8))) __bf16 bf16x8;
typedef __attribute__((ext_vector_type(4))) float f32x4;

#define MFMA16(a, b, c) __builtin_amdgcn_mfma_f32_16x16x32_bf16((a), (b), (c), 0, 0, 0)
#define EXP2(x) __builtin_amdgcn_exp2f(x)

__device__ __forceinline__ void async16(const bf16* g, bf16* l) {
  __builtin_amdgcn_global_load_lds(
      (const __attribute__((address_space(1))) void*)g,
      (__attribute__((address_space(3))) void*)l, 16, 0, 0);
}

// ---------------------------------------------------------------------------
// Convert pass: fp32 -> bf16, activations (3x4M) + weights (4x1M).
// ---------------------------------------------------------------------------
__global__ __launch_bounds__(256) void convert_kernel(
    const float* __restrict__ q, const float* __restrict__ k,
    const float* __restrict__ v, const float* __restrict__ wq,
    const float* __restrict__ wk, const float* __restrict__ wv,
    const float* __restrict__ wo, bf16* __restrict__ dst) {
  size_t idx = ((size_t)blockIdx.x * 256 + threadIdx.x) * 8;
  const float* src;
  size_t off;
  if (idx < 4194304) { src = q; off = idx; }
  else if (idx < 8388608) { src = k; off = idx - 4194304; }
  else if (idx < 12582912) { src = v; off = idx - 8388608; }
  else if (idx < 13631488) { src = wq; off = idx - 12582912; }
  else if (idx < 14680064) { src = wk; off = idx - 13631488; }
  else if (idx < 15728640) { src = wv; off = idx - 14680064; }
  else { src = wo; off = idx - 15728640; }
  float4 a = *(const float4*)(src + off);
  float4 b = *(const float4*)(src + off + 4);
  bf16x8 o;
  o[0] = (bf16)a.x; o[1] = (bf16)a.y; o[2] = (bf16)a.z; o[3] = (bf16)a.w;
  o[4] = (bf16)b.x; o[5] = (bf16)b.y; o[6] = (bf16)b.z; o[7] = (bf16)b.w;
  *(bf16x8*)(dst + idx) = o;
}

// ---------------------------------------------------------------------------
// GEMM 128x128, BK=64, XOR-swizzled LDS. smem passed in (single buffer per
// kernel). m0/n0 passed in (XCD-affinity swizzle done by caller). MODE-2 Ct
// aliases smem.
// ---------------------------------------------------------------------------
template <int MODE>
__device__ __forceinline__ void gemm_body(bf16* smem, const bf16* A,
                                          const bf16* W, const float* bias,
                                          bf16* C, float scale, int m0,
                                          int n0) {
  constexpr int K = 1024;
  bf16* As = smem;
  bf16* Bs = smem + 128 * 64;
  const int t = threadIdx.x;
  const int lane = t & 63, wave = t >> 6;
  const int quad = lane >> 4, l16 = lane & 15;
  const int wm = (wave >> 1) * 64, wn = (wave & 1) * 64;

  const f32x4 zero = {0.f, 0.f, 0.f, 0.f};
  f32x4 acc[4][4];
  for (int i = 0; i < 4; i++)
    for (int j = 0; j < 4; j++) acc[i][j] = zero;

  for (int k0 = 0; k0 < K; k0 += 64) {
    for (int i = 0; i < 4; ++i) {
      int c = i * 256 + t;
      int row = c >> 3, g = c & 7;
      int off = k0 + ((g ^ (row & 7)) * 8);
      async16(A + (size_t)(m0 + row) * K + off, As + c * 8);
      async16(W + (size_t)(n0 + row) * K + off, Bs + c * 8);
    }
    __syncthreads();

    for (int ks = 0; ks < 2; ks++) {
      bf16x8 af[4], bfr[4];
      for (int mb = 0; mb < 4; mb++) {
        int ra = wm + mb * 16 + l16;
        af[mb] = *(const bf16x8*)(As + ra * 64 + ((ks * 4 + quad) ^ (ra & 7)) * 8);
        int rb = wn + mb * 16 + l16;
        bfr[mb] = *(const bf16x8*)(Bs + rb * 64 + ((ks * 4 + quad) ^ (rb & 7)) * 8);
      }
      for (int mb = 0; mb < 4; mb++)
        for (int nb = 0; nb < 4; nb++)
          acc[mb][nb] = MFMA16(af[mb], bfr[nb], acc[mb][nb]);
    }
    __syncthreads();  // also makes smem safe to reuse as Ct
  }

  if constexpr (MODE == 2) {
    bf16* Ct = smem;  // [128 cols][136]
    for (int nb = 0; nb < 4; nb++) {
      int cl = wn + nb * 16 + l16;
      float bv = bias[n0 + cl] * scale;
      for (int mb = 0; mb < 4; mb++) {
        int rowb = wm + mb * 16 + quad * 4;
        bf16x4 v;
        for (int r = 0; r < 4; r++)
          v[r] = (bf16)(acc[mb][nb][r] * scale + bv);
        *(bf16x4*)(Ct + cl * 136 + rowb) = v;
      }
    }
    __syncthreads();
    int c = t >> 1, half = t & 1;
    int colg = n0 + c;
    int hh = colg >> 6, dd = colg & 63;
    int bb = m0 >> 11, s0 = m0 & (S_ - 1);
    bf16* dst = C + (((size_t)(bb * H_ + hh)) * HD_ + dd) * S_ + s0 + half * 64;
    const bf16* srcr = Ct + c * 136 + half * 64;
    for (int j = 0; j < 8; ++j)
      *(bf16x8*)(dst + j * 8) = *(const bf16x8*)(srcr + j * 8);
  } else {
    for (int nb = 0; nb < 4; nb++) {
      int col = n0 + wn + nb * 16 + l16;
      float bv = bias[col] * scale;
      for (int mb = 0; mb < 4; mb++) {
        int rowb = m0 + wm + mb * 16 + quad * 4;
        for (int r = 0; r < 4; r++) {
          int row = rowb + r;
          float o = acc[mb][nb][r] * scale + bv;
          int bb = row >> 11, s = row & (S_ - 1);
          int h = col >> 6, d = col & 63;
          C[(((size_t)(bb * H_ + h)) * S_ + s) * HD_ + d] = (bf16)o;
        }
      }
    }
  }
}

// ---------------------------------------------------------------------------
// qkv: 1D grid 768, XCD-affinity decode. XCD c owns 4 m-blocks x all n per
// z: per-XCD L2 set = A-band 1MB + W_z 2MB = 3MB < 4MB -> re-reads hit L2.
// ---------------------------------------------------------------------------
__global__ __launch_bounds__(256, 4) void qkv_proj_kernel(
    const bf16* Xc, const float* bq, const float* bk, const float* bv,
    bf16* Qo, bf16* Ko, bf16* Vo) {
  __shared__ __align__(16) bf16 smem[128 * 136];  // 34816 B, one per block
  int bid = blockIdx.x;
  int z = bid >> 8;          // 256 blocks per z
  int r = bid & 255;
  int c = r & 7;             // XCD class (dispatch round-robin heuristic)
  int j = r >> 3;            // [0,32)
  int m0 = (c * 4 + (j & 3)) * 128;
  int n0 = (j >> 2) * 128;
  const bf16* A = Xc + (size_t)z * 4194304;
  const bf16* W = Xc + 12582912 + (size_t)z * 1048576;
  if (z == 0)
    gemm_body<1>(smem, A, W, bq, Qo, QSCALE_, m0, n0);  // Q pre-scaled
  else if (z == 1)
    gemm_body<1>(smem, A, W, bk, Ko, 1.0f, m0, n0);
  else
    gemm_body<2>(smem, A, W, bv, Vo, 1.0f, m0, n0);
}

// ---------------------------------------------------------------------------
// out_proj: R14 64x64 tiles. Grid 1024, XCD-affinity decode (XCD c owns 8
// m-blocks x all 16 n: A-band 1MB + W 2MB = 3MB L2-resident). BK=64,
// swizzled, LDS 16KB.
// ---------------------------------------------------------------------------
__global__ __launch_bounds__(256, 4) void out_proj_kernel(const bf16* A,
                                                          const bf16* W,
                                                          const float* bias,
                                                          float* C) {
  constexpr int K = 1024, N = 1024;
  __shared__ __align__(16) bf16 As[64 * 64];
  __shared__ __align__(16) bf16 Bs[64 * 64];
  const int t = threadIdx.x;
  const int lane = t & 63, wave = t >> 6;
  const int quad = lane >> 4, l16 = lane & 15;
  int bid = blockIdx.x;
  int c = bid & 7;
  int j = bid >> 3;  // [0,128)
  const int m0 = (c * 8 + (j & 7)) * 64;
  const int n0 = (j >> 3) * 64;

  const f32x4 zero = {0.f, 0.f, 0.f, 0.f};
  f32x4 acc[4];
  for (int i = 0; i < 4; i++) acc[i] = zero;

  for (int k0 = 0; k0 < K; k0 += 64) {
    for (int i = 0; i < 2; ++i) {
      int cc = i * 256 + t;
      int row = cc >> 3, g = cc & 7;
      int off = k0 + ((g ^ (row & 7)) * 8);
      async16(A + (size_t)(m0 + row) * K + off, As + cc * 8);
      async16(W + (size_t)(n0 + row) * K + off, Bs + cc * 8);
    }
    __syncthreads();

    for (int ks = 0; ks < 2; ks++) {
      int ra = wave * 16 + l16;
      bf16x8 af = *(const bf16x8*)(As + ra * 64 + ((ks * 4 + quad) ^ (ra & 7)) * 8);
      for (int nb = 0; nb < 4; nb++) {
        int rb = nb * 16 + l16;
        bf16x8 bfr =
            *(const bf16x8*)(Bs + rb * 64 + ((ks * 4 + quad) ^ (rb & 7)) * 8);
        acc[nb] = MFMA16(af, bfr, acc[nb]);
      }
    }
    __syncthreads();
  }

  for (int nb = 0; nb < 4; nb++) {
    int col = n0 + nb * 16 + l16;
    float bv = bias[col];
    int rowb = m0 + wave * 16 + quad * 4;
    for (int r = 0; r < 4; r++)
      C[(size_t)(rowb + r) * N + col] = acc[nb][r] + bv;
  }
}

// ---------------------------------------------------------------------------
// Flash attention, softmax-one, S^T order. R18: DOUBLE-BUFFERED K/V staging
// via global_load_lds (T3 minimum 2-phase). R15-R17 proved reg-staged T14
// is compiler-defeated (spill/sink); DMA dbuf is the mechanism the compiler
// can't undo: stage tile t+1 into buf^1 at tile top, compute tile t, then
// ONE barrier/tile — its vmcnt(0) drain lands a full compute phase (~2K cyc)
// after issue, covering L2 latency. Barriers/tile: 2 -> 1.
// LDS: KV dbuf 64KB forces Ps 36.9->16KB: PV split into two 32-key segments
// reusing one per-wave [64][32] P^T buffer (same within-seg layout, same
// in-order-DS write->read guarantee). Total EXACTLY 81920B -> 2 blocks/CU.
// rsL/Ld are epilogue-only overlays of the dbuf region. setprio dropped
// (null on lockstep-barrier waves). Last-iter stage wraps to tile 0 (dead).
// Block = 4 waves = 2 q-halves x 2 key-halves of (128q x 128key); 4
// qsets/wave. Grid 512 = 2/CU. XCD decode id&31 -> (b,h). exp2 (Q
// pre-scaled by log2e); no max-tracking; denom = 1 + sum.
// ---------------------------------------------------------------------------
__device__ __forceinline__ void stage_tile(const bf16* Kp, const bf16* Vp,
                                           int kv, bf16* Ksb, bf16* Vtb,
                                           int t) {
  for (int i = 0; i < 4; ++i) {
    int cc = i * 256 + t;
    int row = cc >> 3, g = cc & 7;
    async16(Kp + (size_t)(kv + row) * HD_ + (g ^ (row & 7)) * 8, Ksb + cc * 8);
  }
  for (int i = 0; i < 4; ++i) {
    int cc = i * 256 + t;
    int d = cc >> 4, g = cc & 15;
    async16(Vp + (size_t)d * S_ + kv + (g ^ (d & 15)) * 8, Vtb + cc * 8);
  }
}

__global__ __launch_bounds__(256, 2) void attn_kernel(
    const bf16* __restrict__ Q, const bf16* __restrict__ Kg,
    const bf16* __restrict__ VTg, bf16* __restrict__ O) {
  // smem layout (bf16 units): buf0 Ks[8192] Vt[8192] | buf1 Ks Vt | Ps[8192]
  // = 40960 units = 81920 B. Epilogue overlays Ld (34816B) + rsL (512B).
  __shared__ __align__(16) bf16 smem[40960];
  const int t = threadIdx.x;
  const int lane = t & 63, wave = t >> 6;
  const int quad = lane >> 4, l16 = lane & 15;
  const int id = blockIdx.x;
  const int bh = id & 31;  // (b,h): fixes XCD class (id%8 = bh%8)
  const int qt = id >> 5;
  const int q0 = qt * 128;
  const int b = bh >> 4, h = bh & 15;
  const int qhalf = wave >> 1, khalf = wave & 1;
  const size_t base = ((size_t)(b * H_ + h)) * S_ * HD_;
  const bf16* Qp = Q + base;
  const bf16* Kp = Kg + base;
  const bf16* Vp = VTg + base;  // [HD][S]

  // Q fragments: 4 qsets of 16 rows; rows q0 + qhalf*64 + s*16 + l16
  bf16x8 aq[4][2];
  for (int s = 0; s < 4; s++) {
    const bf16* qr = Qp + (size_t)(q0 + qhalf * 64 + s * 16 + l16) * HD_;
    aq[s][0] = *(const bf16x8*)(qr + quad * 8);
    aq[s][1] = *(const bf16x8*)(qr + 32 + quad * 8);
  }

  const f32x4 zero = {0.f, 0.f, 0.f, 0.f};
  f32x4 oc[4][4];  // [qset][dim-block]
  for (int s = 0; s < 4; s++)
    for (int d = 0; d < 4; d++) oc[s][d] = zero;
  float rs[4] = {0.f, 0.f, 0.f, 0.f};

  bf16* Pw = smem + 32768 + wave * (64 * 32);  // per-wave P^T [64][32]

  // prologue: stage tile 0 into buf0; single full drain
  stage_tile(Kp, Vp, 0, smem, smem + 8192, t);
  __syncthreads();

  for (int kv0 = 0; kv0 < S_; kv0 += 128) {
    const int cur = (kv0 >> 7) & 1;
    bf16* Ksc = smem + cur * 16384;
    bf16* Vtc = Ksc + 8192;
    bf16* Ksn = smem + (cur ^ 1) * 16384;
    bf16* Vtn = Ksn + 8192;
    // issue next tile's DMA now; drained by THIS tile's end barrier.
    stage_tile(Kp, Vp, (kv0 + 128) & (S_ - 1), Ksn, Vtn, t);

    // S^T = K Q^T over this wave's 64 keys (khalf) x 64 q (qhalf)
    f32x4 sc[4][4];
    for (int s = 0; s < 4; s++)
      for (int nb = 0; nb < 4; nb++) sc[s][nb] = zero;
    for (int ks = 0; ks < 2; ks++) {
      for (int nb = 0; nb < 4; nb++) {
        int row = khalf * 64 + nb * 16 + l16;
        int slot = (ks * 4 + quad) ^ (row & 7);
        bf16x8 kf = *(const bf16x8*)(Ksc + row * 64 + slot * 8);
        for (int s = 0; s < 4; s++)
          sc[s][nb] = MFMA16(kf, aq[s][ks], sc[s][nb]);
      }
    }

    // two 32-key segments: exp2 + P^T write, then PV (Pw reused per seg;
    // wave-private, in-order DS pipe orders write->read->overwrite).
    for (int seg = 0; seg < 2; seg++) {
      for (int s = 0; s < 4; s++) {
        bf16* prow = Pw + (s * 16 + l16) * 32 + quad * 4;
        for (int nbl = 0; nbl < 2; nbl++) {
          int nb = seg * 2 + nbl;
          float p0 = EXP2(sc[s][nb][0]);
          float p1 = EXP2(sc[s][nb][1]);
          float p2 = EXP2(sc[s][nb][2]);
          float p3 = EXP2(sc[s][nb][3]);
          rs[s] += (p0 + p1) + (p2 + p3);
          bf16x4 pv = {(bf16)p0, (bf16)p1, (bf16)p2, (bf16)p3};
          *(bf16x4*)(prow + nbl * 16) = pv;
        }
      }
      bf16x8 vf[4];
      for (int db = 0; db < 4; db++) {
        int row = db * 16 + l16;
        int g = khalf * 8 + seg * 4 + quad;
        vf[db] = *(const bf16x8*)(Vtc + row * 128 + (g ^ (row & 15)) * 8);
      }
      for (int s = 0; s < 4; s++) {
        bf16x8 ap = *(const bf16x8*)(Pw + (s * 16 + l16) * 32 + quad * 8);
        for (int db = 0; db < 4; db++)
          oc[s][db] = MFMA16(ap, vf[db], oc[s][db]);
      }
    }

    // ONE barrier per tile: drains next-tile DMA (issued ~full compute
    // phase ago) + protects buf[cur] before t+2 overwrites it.
    __syncthreads();
  }

  // epilogue: combine key-halves through LDS (overlays the dbuf region;
  // all tile reads completed at the final loop barrier).
  float* Ld = (float*)smem;                 // [2][64][68] fp32 = 34816 B
  float* rsL = (float*)(smem + 17408);      // [2][64] fp32 = 512 B
  if (khalf) {
    for (int s = 0; s < 4; s++) {
      float rtot = rs[s];
      rtot += __shfl_xor(rtot, 16);
      rtot += __shfl_xor(rtot, 32);
      if (quad == 0) rsL[qhalf * 64 + s * 16 + l16] = rtot;
      for (int db = 0; db < 4; db++)
        for (int r = 0; r < 4; r++)
          Ld[(size_t)qhalf * (64 * 68) + (s * 16 + quad * 4 + r) * 68 +
             db * 16 + l16] = oc[s][db][r];
    }
  }
  __syncthreads();
  if (!khalf) {
    for (int s = 0; s < 4; s++) {
      float rtot = rs[s];
      rtot += __shfl_xor(rtot, 16);
      rtot += __shfl_xor(rtot, 32);
      float l_all = 1.f + rtot + rsL[qhalf * 64 + s * 16 + l16];
      for (int r = 0; r < 4; r++) {
        float inv = 1.f / __shfl(l_all, quad * 4 + r);
        int qrow = q0 + qhalf * 64 + s * 16 + quad * 4 + r;
        size_t orow = ((size_t)(b * S_ + qrow) * H_ + h) * HD_;
        for (int db = 0; db < 4; db++) {
          float val = oc[s][db][r] +
                      Ld[(size_t)qhalf * (64 * 68) +
                         (s * 16 + quad * 4 + r) * 68 + db * 16 + l16];
          O[orow + db * 16 + l16] = (bf16)(val * inv);
        }
      }
    }
  }
}

// ---------------------------------------------------------------------------
extern "C" void kernel_launch(void* const* d_in, const int* in_sizes, int n_in,
                              void* d_out, int out_size, void* d_ws,
                              size_t ws_size, hipStream_t stream) {
  const float* query = (const float*)d_in[0];
  const float* key = (const float*)d_in[1];
  const float* value = (const float*)d_in[2];
  const float* bq = (const float*)d_in[4];
  const float* bk = (const float*)d_in[6];
  const float* bv = (const float*)d_in[8];
  const float* bo = (const float*)d_in[10];
  float* out = (float*)d_out;

  // ws layout (bf16 elems): Xc[16.7M] | Qw[4M] | Kw[4M] | Vw[4M] | Ow[4M]
  bf16* Xc = (bf16*)d_ws;
  bf16* Qw = Xc + 16777216;
  const size_t SZ = (size_t)B_ * H_ * S_ * HD_;  // 4M
  bf16* Kw = Qw + SZ;
  bf16* Vw = Kw + SZ;  // V^T, [B,H,HD,S]
  bf16* Ow = Vw + SZ;  // [B,S,H,HD]

  convert_kernel<<<8192, 256, 0, stream>>>(query, key, value,
                                           (const float*)d_in[3],
                                           (const float*)d_in[5],
                                           (const float*)d_in[7],
                                           (const float*)d_in[9], Xc);
  qkv_proj_kernel<<<768, 256, 0, stream>>>(Xc, bq, bk, bv, Qw, Kw, Vw);
  attn_kernel<<<512, 256, 0, stream>>>(Qw, Kw, Vw, Ow);
  out_proj_kernel<<<1024, 256, 0, stream>>>(Ow, Xc + 15728640, bo, out);
}

// Round 7
// 221.786 us; speedup vs baseline: 1.0128x; 1.0128x over previous
//
#include <hip/hip_runtime.h>

#define B_ 2
#define S_ 2048
#define DM_ 1024
#define H_ 16
#define HD_ 64
// Q pre-scale = HD^-0.5 * log2(e) so attention uses exp2 (bare v_exp_f32).
#define QSCALE_ 0.18033688011112042f

// Settled R0-R4: inputs fp32 (bf16-rounded values), output fp32.
typedef __bf16 bf16;
typedef __attribute__((ext_vector_type(4))) __bf16 bf16x4;
typedef __attribute__((ext_vector_type(8))) __bf16 bf16x8;
typedef __attribute__((ext_vector_type(4))) float f32x4;

#define MFMA16(a, b, c) __builtin_amdgcn_mfma_f32_16x16x32_bf16((a), (b), (c), 0, 0, 0)
#define EXP2(x) __builtin_amdgcn_exp2f(x)

__device__ __forceinline__ void async16(const bf16* g, bf16* l) {
  __builtin_amdgcn_global_load_lds(
      (const __attribute__((address_space(1))) void*)g,
      (__attribute__((address_space(3))) void*)l, 16, 0, 0);
}

// ---------------------------------------------------------------------------
// Convert pass: fp32 -> bf16, activations (3x4M) + weights (4x1M).
// ---------------------------------------------------------------------------
__global__ __launch_bounds__(256) void convert_kernel(
    const float* __restrict__ q, const float* __restrict__ k,
    const float* __restrict__ v, const float* __restrict__ wq,
    const float* __restrict__ wk, const float* __restrict__ wv,
    const float* __restrict__ wo, bf16* __restrict__ dst) {
  size_t idx = ((size_t)blockIdx.x * 256 + threadIdx.x) * 8;
  const float* src;
  size_t off;
  if (idx < 4194304) { src = q; off = idx; }
  else if (idx < 8388608) { src = k; off = idx - 4194304; }
  else if (idx < 12582912) { src = v; off = idx - 8388608; }
  else if (idx < 13631488) { src = wq; off = idx - 12582912; }
  else if (idx < 14680064) { src = wk; off = idx - 13631488; }
  else if (idx < 15728640) { src = wv; off = idx - 14680064; }
  else { src = wo; off = idx - 15728640; }
  float4 a = *(const float4*)(src + off);
  float4 b = *(const float4*)(src + off + 4);
  bf16x8 o;
  o[0] = (bf16)a.x; o[1] = (bf16)a.y; o[2] = (bf16)a.z; o[3] = (bf16)a.w;
  o[4] = (bf16)b.x; o[5] = (bf16)b.y; o[6] = (bf16)b.z; o[7] = (bf16)b.w;
  *(bf16x8*)(dst + idx) = o;
}

// ---------------------------------------------------------------------------
// GEMM 128x128, BK=64, XOR-swizzled LDS. smem passed in (single buffer per
// kernel). m0/n0 passed in (XCD-affinity swizzle done by caller). MODE-2 Ct
// aliases smem.
// ---------------------------------------------------------------------------
template <int MODE>
__device__ __forceinline__ void gemm_body(bf16* smem, const bf16* A,
                                          const bf16* W, const float* bias,
                                          bf16* C, float scale, int m0,
                                          int n0) {
  constexpr int K = 1024;
  bf16* As = smem;
  bf16* Bs = smem + 128 * 64;
  const int t = threadIdx.x;
  const int lane = t & 63, wave = t >> 6;
  const int quad = lane >> 4, l16 = lane & 15;
  const int wm = (wave >> 1) * 64, wn = (wave & 1) * 64;

  const f32x4 zero = {0.f, 0.f, 0.f, 0.f};
  f32x4 acc[4][4];
  for (int i = 0; i < 4; i++)
    for (int j = 0; j < 4; j++) acc[i][j] = zero;

  for (int k0 = 0; k0 < K; k0 += 64) {
    for (int i = 0; i < 4; ++i) {
      int c = i * 256 + t;
      int row = c >> 3, g = c & 7;
      int off = k0 + ((g ^ (row & 7)) * 8);
      async16(A + (size_t)(m0 + row) * K + off, As + c * 8);
      async16(W + (size_t)(n0 + row) * K + off, Bs + c * 8);
    }
    __syncthreads();

    for (int ks = 0; ks < 2; ks++) {
      bf16x8 af[4], bfr[4];
      for (int mb = 0; mb < 4; mb++) {
        int ra = wm + mb * 16 + l16;
        af[mb] = *(const bf16x8*)(As + ra * 64 + ((ks * 4 + quad) ^ (ra & 7)) * 8);
        int rb = wn + mb * 16 + l16;
        bfr[mb] = *(const bf16x8*)(Bs + rb * 64 + ((ks * 4 + quad) ^ (rb & 7)) * 8);
      }
      for (int mb = 0; mb < 4; mb++)
        for (int nb = 0; nb < 4; nb++)
          acc[mb][nb] = MFMA16(af[mb], bfr[nb], acc[mb][nb]);
    }
    __syncthreads();  // also makes smem safe to reuse as Ct
  }

  if constexpr (MODE == 2) {
    bf16* Ct = smem;  // [128 cols][136]
    for (int nb = 0; nb < 4; nb++) {
      int cl = wn + nb * 16 + l16;
      float bv = bias[n0 + cl] * scale;
      for (int mb = 0; mb < 4; mb++) {
        int rowb = wm + mb * 16 + quad * 4;
        bf16x4 v;
        for (int r = 0; r < 4; r++)
          v[r] = (bf16)(acc[mb][nb][r] * scale + bv);
        *(bf16x4*)(Ct + cl * 136 + rowb) = v;
      }
    }
    __syncthreads();
    int c = t >> 1, half = t & 1;
    int colg = n0 + c;
    int hh = colg >> 6, dd = colg & 63;
    int bb = m0 >> 11, s0 = m0 & (S_ - 1);
    bf16* dst = C + (((size_t)(bb * H_ + hh)) * HD_ + dd) * S_ + s0 + half * 64;
    const bf16* srcr = Ct + c * 136 + half * 64;
    for (int j = 0; j < 8; ++j)
      *(bf16x8*)(dst + j * 8) = *(const bf16x8*)(srcr + j * 8);
  } else {
    for (int nb = 0; nb < 4; nb++) {
      int col = n0 + wn + nb * 16 + l16;
      float bv = bias[col] * scale;
      for (int mb = 0; mb < 4; mb++) {
        int rowb = m0 + wm + mb * 16 + quad * 4;
        for (int r = 0; r < 4; r++) {
          int row = rowb + r;
          float o = acc[mb][nb][r] * scale + bv;
          int bb = row >> 11, s = row & (S_ - 1);
          int h = col >> 6, d = col & 63;
          C[(((size_t)(bb * H_ + h)) * S_ + s) * HD_ + d] = (bf16)o;
        }
      }
    }
  }
}

// ---------------------------------------------------------------------------
// qkv: 1D grid 768, XCD-affinity decode. XCD c owns 4 m-blocks x all n per
// z: per-XCD L2 set = A-band 1MB + W_z 2MB = 3MB < 4MB -> re-reads hit L2.
// ---------------------------------------------------------------------------
__global__ __launch_bounds__(256, 4) void qkv_proj_kernel(
    const bf16* Xc, const float* bq, const float* bk, const float* bv,
    bf16* Qo, bf16* Ko, bf16* Vo) {
  __shared__ __align__(16) bf16 smem[128 * 136];  // 34816 B, one per block
  int bid = blockIdx.x;
  int z = bid >> 8;          // 256 blocks per z
  int r = bid & 255;
  int c = r & 7;             // XCD class (dispatch round-robin heuristic)
  int j = r >> 3;            // [0,32)
  int m0 = (c * 4 + (j & 3)) * 128;
  int n0 = (j >> 2) * 128;
  const bf16* A = Xc + (size_t)z * 4194304;
  const bf16* W = Xc + 12582912 + (size_t)z * 1048576;
  if (z == 0)
    gemm_body<1>(smem, A, W, bq, Qo, QSCALE_, m0, n0);  // Q pre-scaled
  else if (z == 1)
    gemm_body<1>(smem, A, W, bk, Ko, 1.0f, m0, n0);
  else
    gemm_body<2>(smem, A, W, bv, Vo, 1.0f, m0, n0);
}

// ---------------------------------------------------------------------------
// out_proj: R14 64x64 tiles. Grid 1024, XCD-affinity decode (XCD c owns 8
// m-blocks x all 16 n: A-band 1MB + W 2MB = 3MB L2-resident). BK=64,
// swizzled, LDS 16KB.
// ---------------------------------------------------------------------------
__global__ __launch_bounds__(256, 4) void out_proj_kernel(const bf16* A,
                                                          const bf16* W,
                                                          const float* bias,
                                                          float* C) {
  constexpr int K = 1024, N = 1024;
  __shared__ __align__(16) bf16 As[64 * 64];
  __shared__ __align__(16) bf16 Bs[64 * 64];
  const int t = threadIdx.x;
  const int lane = t & 63, wave = t >> 6;
  const int quad = lane >> 4, l16 = lane & 15;
  int bid = blockIdx.x;
  int c = bid & 7;
  int j = bid >> 3;  // [0,128)
  const int m0 = (c * 8 + (j & 7)) * 64;
  const int n0 = (j >> 3) * 64;

  const f32x4 zero = {0.f, 0.f, 0.f, 0.f};
  f32x4 acc[4];
  for (int i = 0; i < 4; i++) acc[i] = zero;

  for (int k0 = 0; k0 < K; k0 += 64) {
    for (int i = 0; i < 2; ++i) {
      int cc = i * 256 + t;
      int row = cc >> 3, g = cc & 7;
      int off = k0 + ((g ^ (row & 7)) * 8);
      async16(A + (size_t)(m0 + row) * K + off, As + cc * 8);
      async16(W + (size_t)(n0 + row) * K + off, Bs + cc * 8);
    }
    __syncthreads();

    for (int ks = 0; ks < 2; ks++) {
      int ra = wave * 16 + l16;
      bf16x8 af = *(const bf16x8*)(As + ra * 64 + ((ks * 4 + quad) ^ (ra & 7)) * 8);
      for (int nb = 0; nb < 4; nb++) {
        int rb = nb * 16 + l16;
        bf16x8 bfr =
            *(const bf16x8*)(Bs + rb * 64 + ((ks * 4 + quad) ^ (rb & 7)) * 8);
        acc[nb] = MFMA16(af, bfr, acc[nb]);
      }
    }
    __syncthreads();
  }

  for (int nb = 0; nb < 4; nb++) {
    int col = n0 + nb * 16 + l16;
    float bv = bias[col];
    int rowb = m0 + wave * 16 + quad * 4;
    for (int r = 0; r < 4; r++)
      C[(size_t)(rowb + r) * N + col] = acc[nb][r] + bv;
  }
}

// ---------------------------------------------------------------------------
// Flash attention, softmax-one, S^T order. R19: OCCUPANCY restructure.
// R18 disproved the staging-latency theory (1-barrier dbuf = no gain); the
// stall is the per-wave serial chain (QK->exp2->P-LDS->PV) with only 2
// waves/SIMD to interleave (grid 512 x 4 waves = 2 blocks/CU hard cap).
// R19: 1024 blocks x 512 threads (8 waves). Block = 64 q x 128-key tile;
// wave = (qhalf of 32 q) x (key-quarter of 32 keys). Per-wave chain halves
// (16 MFMA + 16 exp2/tile); occupancy doubles: 2 blocks/CU x 8 waves = 16
// waves/CU = 4 waves/SIMD. LDS 53248B = Ks 16K + Vt 16K + Ps 8x[32][40]
// (stride 40 bf16 = 20 dwords, gcd(20,32)=4 -> 2-way = conflict-free;
// R18's stride-32 was the 15.7M-conflict mistake). Single-buffered staging,
// 2 barriers/tile (dbuf proven neutral). Epilogue: 2-stage tree combine of
// the 4 key-quarter partials through LDS overlay. VGPR ~95 <= 128 ->
// launch_bounds(512,4) holds 4 waves/SIMD. XCD decode id&31 -> (b,h).
// ---------------------------------------------------------------------------
__global__ __launch_bounds__(512, 4) void attn_kernel(
    const bf16* __restrict__ Q, const bf16* __restrict__ Kg,
    const bf16* __restrict__ VTg, bf16* __restrict__ O) {
  // bf16 units: Ks[0,8192) Vt[8192,16384) Ps[16384,26624) = 53248 B.
  __shared__ __align__(16) bf16 smem[26624];
  const int t = threadIdx.x;
  const int lane = t & 63, wave = t >> 6;
  const int quad = lane >> 4, l16 = lane & 15;
  const int qh = wave >> 2;   // q-half (32 q rows)
  const int kq = wave & 3;    // key-quarter (32 of 128 tile keys)
  const int id = blockIdx.x;
  const int bh = id & 31;     // (b,h): fixes XCD class (id%8 = bh%8)
  const int qt = id >> 5;     // [0,32): 64-q tiles
  const int q0 = qt * 64;
  const int b = bh >> 4, h = bh & 15;
  const size_t base = ((size_t)(b * H_ + h)) * S_ * HD_;
  const bf16* Qp = Q + base;
  const bf16* Kp = Kg + base;
  const bf16* Vp = VTg + base;  // [HD][S]

  bf16* Ks = smem;
  bf16* Vt = smem + 8192;
  bf16* Pw = smem + 16384 + wave * (32 * 40);  // per-wave P^T [32 q][40]

  // Q fragments: 2 qsets of 16 rows; rows q0 + qh*32 + s*16 + l16
  bf16x8 aq[2][2];
  for (int s = 0; s < 2; s++) {
    const bf16* qr = Qp + (size_t)(q0 + qh * 32 + s * 16 + l16) * HD_;
    aq[s][0] = *(const bf16x8*)(qr + quad * 8);
    aq[s][1] = *(const bf16x8*)(qr + 32 + quad * 8);
  }

  const f32x4 zero = {0.f, 0.f, 0.f, 0.f};
  f32x4 oc[2][4];  // [qset][dim-block] partial over this wave's 32 keys
  for (int s = 0; s < 2; s++)
    for (int d = 0; d < 4; d++) oc[s][d] = zero;
  float rs[2] = {0.f, 0.f};

  for (int kv0 = 0; kv0 < S_; kv0 += 128) {
    // stage K (128x64) + V^T (64x128), XOR-swizzled granules, 512 threads
    for (int i = 0; i < 2; ++i) {
      int cc = i * 512 + t;
      int row = cc >> 3, g = cc & 7;
      async16(Kp + (size_t)(kv0 + row) * HD_ + (g ^ (row & 7)) * 8,
              Ks + cc * 8);
    }
    for (int i = 0; i < 2; ++i) {
      int cc = i * 512 + t;
      int d = cc >> 4, g = cc & 15;
      async16(Vp + (size_t)d * S_ + kv0 + (g ^ (d & 15)) * 8, Vt + cc * 8);
    }
    __syncthreads();

    // S^T = K Q^T over this wave's 32 keys (kq) x 32 q (qh)
    f32x4 sc[2][2];
    for (int s = 0; s < 2; s++)
      for (int nb = 0; nb < 2; nb++) sc[s][nb] = zero;
    for (int ks = 0; ks < 2; ks++) {
      for (int nb = 0; nb < 2; nb++) {
        int row = kq * 32 + nb * 16 + l16;
        int slot = (ks * 4 + quad) ^ (row & 7);
        bf16x8 kf = *(const bf16x8*)(Ks + row * 64 + slot * 8);
        for (int s = 0; s < 2; s++)
          sc[s][nb] = MFMA16(kf, aq[s][ks], sc[s][nb]);
      }
    }

    // exp2 + packed P^T write (rows = q local 0..31, cols = 32 local keys)
    for (int s = 0; s < 2; s++) {
      bf16* prow = Pw + (s * 16 + l16) * 40 + quad * 4;
      for (int nb = 0; nb < 2; nb++) {
        float p0 = EXP2(sc[s][nb][0]);
        float p1 = EXP2(sc[s][nb][1]);
        float p2 = EXP2(sc[s][nb][2]);
        float p3 = EXP2(sc[s][nb][3]);
        rs[s] += (p0 + p1) + (p2 + p3);
        bf16x4 pv = {(bf16)p0, (bf16)p1, (bf16)p2, (bf16)p3};
        *(bf16x4*)(prow + nb * 16) = pv;
      }
    }
    // Pw wave-private; in-order DS pipe orders write->read (no barrier).

    // O += P V over this wave's 32 keys; vf shared across 2 qsets
    bf16x8 vf[4];
    for (int db = 0; db < 4; db++) {
      int row = db * 16 + l16;
      int g = kq * 4 + quad;
      vf[db] = *(const bf16x8*)(Vt + row * 128 + (g ^ (row & 15)) * 8);
    }
    for (int s = 0; s < 2; s++) {
      bf16x8 ap = *(const bf16x8*)(Pw + (s * 16 + l16) * 40 + quad * 8);
      for (int db = 0; db < 4; db++)
        oc[s][db] = MFMA16(ap, vf[db], oc[s][db]);
    }

    __syncthreads();  // all reads done before next tile's staging overwrites
  }

  // per-wave denominators: reduce rs over quads (keys quad*4+r, nb*16)
  float rtot[2];
  for (int s = 0; s < 2; s++) {
    float v = rs[s];
    v += __shfl_xor(v, 16);
    v += __shfl_xor(v, 32);
    rtot[s] = v;
  }

  // epilogue: tree-combine the 4 key-quarter partials through LDS overlay.
  // Ld [2 qh][2 pair][32 q][68] f32 = 34816 B; rsL [2][2][32] f32 = 512 B.
  float* Ld = (float*)smem;
  float* rsL = (float*)(smem + 17408);

  if (kq & 1) {  // stage 1: odd quarters publish
    float* Lw = Ld + (size_t)((qh * 2 + (kq >> 1)) * 32) * 68;
    for (int s = 0; s < 2; s++) {
      for (int db = 0; db < 4; db++)
        for (int r = 0; r < 4; r++)
          Lw[(s * 16 + quad * 4 + r) * 68 + db * 16 + l16] = oc[s][db][r];
      if (quad == 0) rsL[(qh * 2 + (kq >> 1)) * 32 + s * 16 + l16] = rtot[s];
    }
  }
  __syncthreads();
  if (!(kq & 1)) {  // stage 2: even quarters absorb their partner
    float* Lr = Ld + (size_t)((qh * 2 + (kq >> 1)) * 32) * 68;
    for (int s = 0; s < 2; s++) {
      for (int db = 0; db < 4; db++)
        for (int r = 0; r < 4; r++)
          oc[s][db][r] += Lr[(s * 16 + quad * 4 + r) * 68 + db * 16 + l16];
      rtot[s] += rsL[(qh * 2 + (kq >> 1)) * 32 + s * 16 + l16];
    }
  }
  if (kq == 2) {  // publish combined (kq2+kq3) into slot [qh][1]
    float* Lw = Ld + (size_t)((qh * 2 + 1) * 32) * 68;
    for (int s = 0; s < 2; s++) {
      for (int db = 0; db < 4; db++)
        for (int r = 0; r < 4; r++)
          Lw[(s * 16 + quad * 4 + r) * 68 + db * 16 + l16] = oc[s][db][r];
      if (quad == 0) rsL[(qh * 2 + 1) * 32 + s * 16 + l16] = rtot[s];
    }
  }
  __syncthreads();
  if (kq == 0) {  // stage 3: finalize
    float* Lr = Ld + (size_t)((qh * 2 + 1) * 32) * 68;
    for (int s = 0; s < 2; s++) {
      float l_all = 1.f + rtot[s] + rsL[(qh * 2 + 1) * 32 + s * 16 + l16];
      for (int r = 0; r < 4; r++) {
        float inv = 1.f / __shfl(l_all, quad * 4 + r);
        int qrow = q0 + qh * 32 + s * 16 + quad * 4 + r;
        size_t orow = ((size_t)(b * S_ + qrow) * H_ + h) * HD_;
        for (int db = 0; db < 4; db++) {
          float val = oc[s][db][r] +
                      Lr[(s * 16 + quad * 4 + r) * 68 + db * 16 + l16];
          O[orow + db * 16 + l16] = (bf16)(val * inv);
        }
      }
    }
  }
}

// ---------------------------------------------------------------------------
extern "C" void kernel_launch(void* const* d_in, const int* in_sizes, int n_in,
                              void* d_out, int out_size, void* d_ws,
                              size_t ws_size, hipStream_t stream) {
  const float* query = (const float*)d_in[0];
  const float* key = (const float*)d_in[1];
  const float* value = (const float*)d_in[2];
  const float* bq = (const float*)d_in[4];
  const float* bk = (const float*)d_in[6];
  const float* bv = (const float*)d_in[8];
  const float* bo = (const float*)d_in[10];
  float* out = (float*)d_out;

  // ws layout (bf16 elems): Xc[16.7M] | Qw[4M] | Kw[4M] | Vw[4M] | Ow[4M]
  bf16* Xc = (bf16*)d_ws;
  bf16* Qw = Xc + 16777216;
  const size_t SZ = (size_t)B_ * H_ * S_ * HD_;  // 4M
  bf16* Kw = Qw + SZ;
  bf16* Vw = Kw + SZ;  // V^T, [B,H,HD,S]
  bf16* Ow = Vw + SZ;  // [B,S,H,HD]

  convert_kernel<<<8192, 256, 0, stream>>>(query, key, value,
                                           (const float*)d_in[3],
                                           (const float*)d_in[5],
                                           (const float*)d_in[7],
                                           (const float*)d_in[9], Xc);
  qkv_proj_kernel<<<768, 256, 0, stream>>>(Xc, bq, bk, bv, Qw, Kw, Vw);
  attn_kernel<<<1024, 512, 0, stream>>>(Qw, Kw, Vw, Ow);
  out_proj_kernel<<<1024, 256, 0, stream>>>(Ow, Xc + 15728640, bo, out);
}